// Round 3
// baseline (503.664 us; speedup 1.0000x reference)
//
#include <hip/hip_runtime.h>
#include <hip/hip_bf16.h>

// CausalSelfAttention (B=2,T=2048,C=1024,H=16,DH=64) — bf16 MFMA implementation.
// ws layout (bytes):
//   [0,8M)    Xb  : x as bf16 [4096][1024]   (reused as Ab = attention out)
//   [8M,14M)  Wt  : [wq;wk;wv]^T bf16 [3072][1024]  (Wt[n][k]=W[k][n])
//   [14M,16M) Wot : wo^T bf16 [1024][1024]
//   [16M,24M) Qg  : [b][h][t][d] bf16 (post-RoPE)
//   [24M,32M) Kg  : [b][h][t][d] bf16 (post-RoPE)
//   [32M,40M) Vg  : [b][h][t][d] bf16
//   [40M,48M) Vt  : [b][h][d][t] bf16

typedef __attribute__((ext_vector_type(8))) short bf16x8;
typedef __attribute__((ext_vector_type(4))) float f32x4;
typedef unsigned short u16;

#define DEV __device__ __forceinline__

DEV u16 f2bf(float f) {
  __hip_bfloat16 h = __float2bfloat16(f);
  u16 u; __builtin_memcpy(&u, &h, 2); return u;
}

// ---------------- x fp32 -> bf16 ----------------
__global__ __launch_bounds__(256) void k_cvt(const float* __restrict__ in,
                                             u16* __restrict__ out) {
  int i = (blockIdx.x * 256 + threadIdx.x) * 8;
  float4 a = *(const float4*)(in + i);
  float4 b = *(const float4*)(in + i + 4);
  union { u16 us[8]; uint4 v; } pk;
  pk.us[0] = f2bf(a.x); pk.us[1] = f2bf(a.y); pk.us[2] = f2bf(a.z); pk.us[3] = f2bf(a.w);
  pk.us[4] = f2bf(b.x); pk.us[5] = f2bf(b.y); pk.us[6] = f2bf(b.z); pk.us[7] = f2bf(b.w);
  *(uint4*)(out + i) = pk.v;
}

// ---------------- weight transpose + convert ----------------
// src [1024][1024] fp32 row-major -> dst [1024][1024] bf16 with dst[n][k]=src[k][n]
__global__ __launch_bounds__(256) void k_trw(const float* __restrict__ wq,
                                             const float* __restrict__ wk,
                                             const float* __restrict__ wv,
                                             const float* __restrict__ wo,
                                             u16* __restrict__ Wt,
                                             u16* __restrict__ Wot) {
  __shared__ float tile[32][33];
  const int z = blockIdx.z;
  const float* src = (z == 0) ? wq : (z == 1) ? wk : (z == 2) ? wv : wo;
  u16* dst = (z < 3) ? (Wt + (size_t)z * 1024 * 1024) : Wot;
  const int n0 = blockIdx.x * 32, k0 = blockIdx.y * 32;
  const int tx = threadIdx.x & 31, ty = threadIdx.x >> 5;
#pragma unroll
  for (int rr = 0; rr < 4; ++rr) {
    int k = ty + rr * 8;
    tile[k][tx] = src[(size_t)(k0 + k) * 1024 + n0 + tx];
  }
  __syncthreads();
#pragma unroll
  for (int rr = 0; rr < 4; ++rr) {
    int n = ty + rr * 8;
    dst[(size_t)(n0 + n) * 1024 + k0 + tx] = f2bf(tile[tx][n]);
  }
}

// ---------------- V transpose: [b][h][t][d] -> [b][h][d][t] ----------------
__global__ __launch_bounds__(256) void k_trv(const u16* __restrict__ Vg,
                                             u16* __restrict__ Vt) {
  __shared__ u16 tile[64][72];
  const int tid = threadIdx.x;
  const int bh = blockIdx.y;
  const int t0 = blockIdx.x * 64;
  const int r = tid >> 2, q = tid & 3;
  const u16* src = &Vg[((size_t)bh * 2048 + t0 + r) * 64 + q * 16];
  uint4 u0 = *(const uint4*)src;
  uint4 u1 = *(const uint4*)(src + 8);
  *(uint4*)&tile[r][q * 16] = u0;
  *(uint4*)&tile[r][q * 16 + 8] = u1;
  __syncthreads();
  const int d = tid >> 2;
  union { u16 us[16]; uint4 v[2]; } pk;
#pragma unroll
  for (int i = 0; i < 16; ++i) pk.us[i] = tile[q * 16 + i][d];
  u16* dst = &Vt[((size_t)bh * 64 + d) * 2048 + t0 + q * 16];
  *(uint4*)dst = pk.v[0];
  *(uint4*)(dst + 8) = pk.v[1];
}

// ---------------- GEMM: C[M][*] = A[M][1024] x Bt[n][1024]^T ----------------
// EPI 0: fused QKV epilogue (bias + RoPE + scatter to Qg/Kg/Vg)
// EPI 1: output projection epilogue (bias + fp32 store)
template <int EPI>
__global__ __launch_bounds__(256) void k_gemm(
    const u16* __restrict__ A, const u16* __restrict__ Bt,
    const float* __restrict__ b0, const float* __restrict__ b1,
    const float* __restrict__ b2, const float* __restrict__ fcos,
    const float* __restrict__ fsin, u16* __restrict__ Qg, u16* __restrict__ Kg,
    u16* __restrict__ Vg, float* __restrict__ outF) {
  __shared__ u16 As[128 * 40];
  __shared__ u16 Bs[128 * 40];
  const int tid = threadIdx.x, lane = tid & 63, wid = tid >> 6;
  const int wm = wid >> 1, wn = wid & 1;
  const int lr = lane & 15, lg = lane >> 4;
  const int m0 = blockIdx.y * 128, n0 = blockIdx.x * 128;
  const int K = 1024;
  f32x4 acc[4][4] = {};

  const int r0 = tid >> 2, c0 = tid & 3;  // 512 16B-chunks, 2 per thread
  uint4 pa[2], pb[2];
#pragma unroll
  for (int c = 0; c < 2; ++c) {
    int row = c * 64 + r0;
    pa[c] = *(const uint4*)&A[(size_t)(m0 + row) * K + c0 * 8];
    pb[c] = *(const uint4*)&Bt[(size_t)(n0 + row) * K + c0 * 8];
  }
  for (int kt = 0; kt < 32; ++kt) {
    __syncthreads();
#pragma unroll
    for (int c = 0; c < 2; ++c) {
      int row = c * 64 + r0;
      *(uint4*)&As[row * 40 + c0 * 8] = pa[c];
      *(uint4*)&Bs[row * 40 + c0 * 8] = pb[c];
    }
    if (kt < 31) {
      int k0 = (kt + 1) * 32;
#pragma unroll
      for (int c = 0; c < 2; ++c) {
        int row = c * 64 + r0;
        pa[c] = *(const uint4*)&A[(size_t)(m0 + row) * K + k0 + c0 * 8];
        pb[c] = *(const uint4*)&Bt[(size_t)(n0 + row) * K + k0 + c0 * 8];
      }
    }
    __syncthreads();
    bf16x8 af[4], bfr[4];
#pragma unroll
    for (int i = 0; i < 4; ++i)
      af[i] = *(const bf16x8*)&As[(wm * 64 + i * 16 + lr) * 40 + lg * 8];
#pragma unroll
    for (int j = 0; j < 4; ++j)
      bfr[j] = *(const bf16x8*)&Bs[(wn * 64 + j * 16 + lr) * 40 + lg * 8];
#pragma unroll
    for (int i = 0; i < 4; ++i)
#pragma unroll
      for (int j = 0; j < 4; ++j)
        acc[i][j] = __builtin_amdgcn_mfma_f32_16x16x32_bf16(af[i], bfr[j],
                                                            acc[i][j], 0, 0, 0);
  }

  if constexpr (EPI == 0) {
#pragma unroll
    for (int i = 0; i < 4; ++i) {
#pragma unroll
      for (int j = 0; j < 4; ++j) {
        f32x4 v = acc[i][j];
        int n = n0 + wn * 64 + j * 16 + lr;
        int mat = n >> 10, nn = n & 1023;
        int h = nn >> 6, d = nn & 63;
        float bval = (mat == 0 ? b0 : (mat == 1 ? b1 : b2))[nn];
        int mb = m0 + wm * 64 + i * 16 + lg * 4;
        if (mat < 2) {  // Q or K: RoPE (even/odd feature pair = adjacent lanes)
          int p = d >> 1;
          float sgn = (d & 1) ? 1.0f : -1.0f;
          u16* dst = (mat == 0) ? Qg : Kg;
#pragma unroll
          for (int r = 0; r < 4; ++r) {
            int m = mb + r, t = m & 2047, b = m >> 11;
            float val = v[r] + bval;
            float c = fcos[t * 32 + p], s = fsin[t * 32 + p];
            float partner = __shfl_xor(val, 1);
            float rv = val * c + sgn * partner * s;
            dst[((size_t)(b * 16 + h) * 2048 + t) * 64 + d] = f2bf(rv);
          }
        } else {  // V
#pragma unroll
          for (int r = 0; r < 4; ++r) {
            int m = mb + r, t = m & 2047, b = m >> 11;
            Vg[((size_t)(b * 16 + h) * 2048 + t) * 64 + d] = f2bf(v[r] + bval);
          }
        }
      }
    }
  } else {
#pragma unroll
    for (int i = 0; i < 4; ++i) {
#pragma unroll
      for (int j = 0; j < 4; ++j) {
        int n = n0 + wn * 64 + j * 16 + lr;
        float bval = b0[n];
        int mb = m0 + wm * 64 + i * 16 + lg * 4;
#pragma unroll
        for (int r = 0; r < 4; ++r)
          outF[(size_t)(mb + r) * 1024 + n] = acc[i][j][r] + bval;
      }
    }
  }
}

// ---------------- flash attention ----------------
// grid: (T/64, B*H). 4 waves/block, wave w owns q rows [q0+16w, q0+16w+16).
__global__ __launch_bounds__(256) void k_attn(const u16* __restrict__ Qg,
                                              const u16* __restrict__ Kg,
                                              const u16* __restrict__ Vt,
                                              u16* __restrict__ Ab) {
  __shared__ u16 P_lds[4][16][72];
  const int tid = threadIdx.x, lane = tid & 63, w = tid >> 6;
  const int lr = lane & 15, lg = lane >> 4;
  const int q0 = blockIdx.x * 64;
  const int bh = blockIdx.y;  // b*16+h
  const size_t qkbase = (size_t)bh * 2048 * 64;
  const int qrow = q0 + w * 16;

  bf16x8 aQ[2];
#pragma unroll
  for (int c = 0; c < 2; ++c)
    aQ[c] = *(const bf16x8*)&Qg[qkbase + (size_t)(qrow + lr) * 64 + lg * 8 + c * 32];

  f32x4 acc_o[4] = {};
  float m_run[4], l_run[4];
#pragma unroll
  for (int r = 0; r < 4; ++r) { m_run[r] = -1e30f; l_run[r] = 0.f; }

  const int ntiles = q0 / 64 + 1;
  for (int kt = 0; kt < ntiles; ++kt) {
    const int kv0 = kt * 64;
    const bool last = (kt == ntiles - 1);
    float p[4][4];
#pragma unroll
    for (int nt = 0; nt < 4; ++nt) {
      const u16* kp = &Kg[qkbase + (size_t)(kv0 + nt * 16 + lr) * 64 + lg * 8];
      bf16x8 k0v = *(const bf16x8*)kp;
      bf16x8 k1v = *(const bf16x8*)(kp + 32);
      f32x4 s = {};
      s = __builtin_amdgcn_mfma_f32_16x16x32_bf16(aQ[0], k0v, s, 0, 0, 0);
      s = __builtin_amdgcn_mfma_f32_16x16x32_bf16(aQ[1], k1v, s, 0, 0, 0);
#pragma unroll
      for (int r = 0; r < 4; ++r) {
        float x = s[r] * 0.125f;
        if (last && (kv0 + nt * 16 + lr > qrow + lg * 4 + r)) x = -1e30f;
        p[nt][r] = x;
      }
    }
    // online softmax (row r lives across the 16 lanes of each 16-lane group)
    float pm[4], alpha[4], rs[4];
#pragma unroll
    for (int r = 0; r < 4; ++r)
      pm[r] = fmaxf(fmaxf(p[0][r], p[1][r]), fmaxf(p[2][r], p[3][r]));
#pragma unroll
    for (int off = 1; off < 16; off <<= 1)
#pragma unroll
      for (int r = 0; r < 4; ++r) pm[r] = fmaxf(pm[r], __shfl_xor(pm[r], off));
#pragma unroll
    for (int r = 0; r < 4; ++r) {
      float mn = fmaxf(m_run[r], pm[r]);
      alpha[r] = __expf(m_run[r] - mn);
      m_run[r] = mn;
    }
#pragma unroll
    for (int nt = 0; nt < 4; ++nt)
#pragma unroll
      for (int r = 0; r < 4; ++r) p[nt][r] = __expf(p[nt][r] - m_run[r]);
#pragma unroll
    for (int r = 0; r < 4; ++r) rs[r] = (p[0][r] + p[1][r]) + (p[2][r] + p[3][r]);
#pragma unroll
    for (int off = 1; off < 16; off <<= 1)
#pragma unroll
      for (int r = 0; r < 4; ++r) rs[r] += __shfl_xor(rs[r], off);
#pragma unroll
    for (int r = 0; r < 4; ++r) l_run[r] = l_run[r] * alpha[r] + rs[r];
#pragma unroll
    for (int j = 0; j < 4; ++j)
#pragma unroll
      for (int r = 0; r < 4; ++r) acc_o[j][r] *= alpha[r];
    // P -> LDS (per-wave slice), re-fragment as MFMA A operand
#pragma unroll
    for (int nt = 0; nt < 4; ++nt)
#pragma unroll
      for (int r = 0; r < 4; ++r)
        P_lds[w][lg * 4 + r][nt * 16 + lr] = f2bf(p[nt][r]);
    asm volatile("s_waitcnt lgkmcnt(0)" ::: "memory");
    __builtin_amdgcn_sched_barrier(0);
    bf16x8 aP0 = *(const bf16x8*)&P_lds[w][lr][lg * 8];
    bf16x8 aP1 = *(const bf16x8*)&P_lds[w][lr][lg * 8 + 32];
#pragma unroll
    for (int j = 0; j < 4; ++j) {
      const u16* vp = &Vt[(size_t)(bh * 64 + j * 16 + lr) * 2048 + kv0 + lg * 8];
      bf16x8 v0 = *(const bf16x8*)vp;
      bf16x8 v1 = *(const bf16x8*)(vp + 32);
      acc_o[j] = __builtin_amdgcn_mfma_f32_16x16x32_bf16(aP0, v0, acc_o[j], 0, 0, 0);
      acc_o[j] = __builtin_amdgcn_mfma_f32_16x16x32_bf16(aP1, v1, acc_o[j], 0, 0, 0);
    }
  }
  const int b = bh >> 4, h = bh & 15;
#pragma unroll
  for (int j = 0; j < 4; ++j)
#pragma unroll
    for (int r = 0; r < 4; ++r) {
      int q = qrow + lg * 4 + r;
      float val = acc_o[j][r] / l_run[r];
      Ab[(size_t)(b * 2048 + q) * 1024 + h * 64 + j * 16 + lr] = f2bf(val);
    }
}

extern "C" void kernel_launch(void* const* d_in, const int* in_sizes, int n_in,
                              void* d_out, int out_size, void* d_ws,
                              size_t ws_size, hipStream_t stream) {
  (void)in_sizes; (void)n_in; (void)out_size; (void)ws_size;
  const float* x = (const float*)d_in[0];
  // d_in[1] = mask (tril) — causal handled analytically
  const float* fcos = (const float*)d_in[2];
  const float* fsin = (const float*)d_in[3];
  const float* wq = (const float*)d_in[4];
  const float* bq = (const float*)d_in[5];
  const float* wk = (const float*)d_in[6];
  const float* bk = (const float*)d_in[7];
  const float* wv = (const float*)d_in[8];
  const float* bv = (const float*)d_in[9];
  const float* wo = (const float*)d_in[10];
  const float* bo = (const float*)d_in[11];
  float* out = (float*)d_out;
  char* ws = (char*)d_ws;
  const size_t MB = 1024 * 1024;
  u16* Xb  = (u16*)(ws);
  u16* Wt  = (u16*)(ws + 8 * MB);
  u16* Wot = (u16*)(ws + 14 * MB);
  u16* Qg  = (u16*)(ws + 16 * MB);
  u16* Kg  = (u16*)(ws + 24 * MB);
  u16* Vg  = (u16*)(ws + 32 * MB);
  u16* Vt  = (u16*)(ws + 40 * MB);
  u16* Ab  = Xb;  // x no longer needed after QKV GEMM

  k_cvt<<<2048, 256, 0, stream>>>(x, Xb);
  k_trw<<<dim3(32, 32, 4), 256, 0, stream>>>(wq, wk, wv, wo, Wt, Wot);
  k_gemm<0><<<dim3(24, 32), 256, 0, stream>>>(Xb, Wt, bq, bk, bv, fcos, fsin,
                                              Qg, Kg, Vg, nullptr);
  k_trv<<<dim3(32, 32), 256, 0, stream>>>(Vg, Vt);
  k_attn<<<dim3(32, 32), 256, 0, stream>>>(Qg, Kg, Vt, Ab);
  k_gemm<1><<<dim3(8, 32), 256, 0, stream>>>(Ab, Wot, bo, nullptr, nullptr,
                                             nullptr, nullptr, nullptr, nullptr,
                                             nullptr, out);
}

// Round 5
// 394.833 us; speedup vs baseline: 1.2756x; 1.2756x over previous
//
#include <hip/hip_runtime.h>
#include <hip/hip_bf16.h>

// CausalSelfAttention (B=2,T=2048,C=1024,H=16,DH=64) — bf16 MFMA implementation.
// ws layout (bytes):
//   [0,8M)    Xb  : x as bf16 [4096][1024]   (reused as Ab = attention out)
//   [8M,14M)  Wt  : [wq;wk;wv]^T bf16 [3072][1024]  (Wt[n][k]=W[k][n])
//   [14M,16M) Wot : wo^T bf16 [1024][1024]
//   [16M,24M) Qg  : [b][h][t][d] bf16 (post-RoPE)
//   [24M,32M) Kg  : [b][h][t][d] bf16 (post-RoPE)
//   [32M,40M) Vg  : [b][h][t][d] bf16
//   [40M,48M) Vt  : [b][h][d][t] bf16

typedef __attribute__((ext_vector_type(8))) short bf16x8;
typedef __attribute__((ext_vector_type(4))) float f32x4;
typedef unsigned short u16;

#define DEV __device__ __forceinline__

DEV u16 f2bf(float f) {
  __hip_bfloat16 h = __float2bfloat16(f);
  u16 u; __builtin_memcpy(&u, &h, 2); return u;
}

// ---------------- x fp32 -> bf16 ----------------
__global__ __launch_bounds__(256) void k_cvt(const float* __restrict__ in,
                                             u16* __restrict__ out) {
  int i = (blockIdx.x * 256 + threadIdx.x) * 8;
  float4 a = *(const float4*)(in + i);
  float4 b = *(const float4*)(in + i + 4);
  union { u16 us[8]; uint4 v; } pk;
  pk.us[0] = f2bf(a.x); pk.us[1] = f2bf(a.y); pk.us[2] = f2bf(a.z); pk.us[3] = f2bf(a.w);
  pk.us[4] = f2bf(b.x); pk.us[5] = f2bf(b.y); pk.us[6] = f2bf(b.z); pk.us[7] = f2bf(b.w);
  *(uint4*)(out + i) = pk.v;
}

// ---------------- weight transpose + convert ----------------
// src [1024][1024] fp32 row-major -> dst [1024][1024] bf16 with dst[n][k]=src[k][n]
__global__ __launch_bounds__(256) void k_trw(const float* __restrict__ wq,
                                             const float* __restrict__ wk,
                                             const float* __restrict__ wv,
                                             const float* __restrict__ wo,
                                             u16* __restrict__ Wt,
                                             u16* __restrict__ Wot) {
  __shared__ float tile[32][33];
  const int z = blockIdx.z;
  const float* src = (z == 0) ? wq : (z == 1) ? wk : (z == 2) ? wv : wo;
  u16* dst = (z < 3) ? (Wt + (size_t)z * 1024 * 1024) : Wot;
  const int n0 = blockIdx.x * 32, k0 = blockIdx.y * 32;
  const int tx = threadIdx.x & 31, ty = threadIdx.x >> 5;
#pragma unroll
  for (int rr = 0; rr < 4; ++rr) {
    int k = ty + rr * 8;
    tile[k][tx] = src[(size_t)(k0 + k) * 1024 + n0 + tx];
  }
  __syncthreads();
#pragma unroll
  for (int rr = 0; rr < 4; ++rr) {
    int n = ty + rr * 8;
    dst[(size_t)(n0 + n) * 1024 + k0 + tx] = f2bf(tile[tx][n]);
  }
}

// ---------------- V transpose: [b][h][t][d] -> [b][h][d][t] ----------------
__global__ __launch_bounds__(256) void k_trv(const u16* __restrict__ Vg,
                                             u16* __restrict__ Vt) {
  __shared__ u16 tile[64][72];
  const int tid = threadIdx.x;
  const int bh = blockIdx.y;
  const int t0 = blockIdx.x * 64;
  const int r = tid >> 2, q = tid & 3;
  const u16* src = &Vg[((size_t)bh * 2048 + t0 + r) * 64 + q * 16];
  uint4 u0 = *(const uint4*)src;
  uint4 u1 = *(const uint4*)(src + 8);
  *(uint4*)&tile[r][q * 16] = u0;
  *(uint4*)&tile[r][q * 16 + 8] = u1;
  __syncthreads();
  const int d = tid >> 2;
  union { u16 us[16]; uint4 v[2]; } pk;
#pragma unroll
  for (int i = 0; i < 16; ++i) pk.us[i] = tile[q * 16 + i][d];
  u16* dst = &Vt[((size_t)bh * 64 + d) * 2048 + t0 + q * 16];
  *(uint4*)dst = pk.v[0];
  *(uint4*)(dst + 8) = pk.v[1];
}

// ---------------- GEMM: C[M][*] = A[M][1024] x Bt[n][1024]^T ----------------
// EPI 0: fused QKV epilogue (bias + RoPE + scatter to Qg/Kg/Vg)
// EPI 1: output projection epilogue (bias + fp32 store)
template <int EPI>
__global__ __launch_bounds__(256) void k_gemm(
    const u16* __restrict__ A, const u16* __restrict__ Bt,
    const float* __restrict__ b0, const float* __restrict__ b1,
    const float* __restrict__ b2, const float* __restrict__ fcos,
    const float* __restrict__ fsin, u16* __restrict__ Qg, u16* __restrict__ Kg,
    u16* __restrict__ Vg, float* __restrict__ outF) {
  __shared__ u16 As[128 * 40];
  __shared__ u16 Bs[128 * 40];
  const int tid = threadIdx.x, lane = tid & 63, wid = tid >> 6;
  const int wm = wid >> 1, wn = wid & 1;
  const int lr = lane & 15, lg = lane >> 4;
  const int m0 = blockIdx.y * 128, n0 = blockIdx.x * 128;
  const int K = 1024;
  f32x4 acc[4][4] = {};

  const int r0 = tid >> 2, c0 = tid & 3;  // 512 16B-chunks, 2 per thread
  uint4 pa[2], pb[2];
#pragma unroll
  for (int c = 0; c < 2; ++c) {
    int row = c * 64 + r0;
    pa[c] = *(const uint4*)&A[(size_t)(m0 + row) * K + c0 * 8];
    pb[c] = *(const uint4*)&Bt[(size_t)(n0 + row) * K + c0 * 8];
  }
  for (int kt = 0; kt < 32; ++kt) {
    __syncthreads();
#pragma unroll
    for (int c = 0; c < 2; ++c) {
      int row = c * 64 + r0;
      *(uint4*)&As[row * 40 + c0 * 8] = pa[c];
      *(uint4*)&Bs[row * 40 + c0 * 8] = pb[c];
    }
    if (kt < 31) {
      int k0 = (kt + 1) * 32;
#pragma unroll
      for (int c = 0; c < 2; ++c) {
        int row = c * 64 + r0;
        pa[c] = *(const uint4*)&A[(size_t)(m0 + row) * K + k0 + c0 * 8];
        pb[c] = *(const uint4*)&Bt[(size_t)(n0 + row) * K + k0 + c0 * 8];
      }
    }
    __syncthreads();
    bf16x8 af[4], bfr[4];
#pragma unroll
    for (int i = 0; i < 4; ++i)
      af[i] = *(const bf16x8*)&As[(wm * 64 + i * 16 + lr) * 40 + lg * 8];
#pragma unroll
    for (int j = 0; j < 4; ++j)
      bfr[j] = *(const bf16x8*)&Bs[(wn * 64 + j * 16 + lr) * 40 + lg * 8];
#pragma unroll
    for (int i = 0; i < 4; ++i)
#pragma unroll
      for (int j = 0; j < 4; ++j)
        acc[i][j] = __builtin_amdgcn_mfma_f32_16x16x32_bf16(af[i], bfr[j],
                                                            acc[i][j], 0, 0, 0);
  }

  if constexpr (EPI == 0) {
#pragma unroll
    for (int i = 0; i < 4; ++i) {
#pragma unroll
      for (int j = 0; j < 4; ++j) {
        f32x4 v = acc[i][j];
        int n = n0 + wn * 64 + j * 16 + lr;
        int mat = n >> 10, nn = n & 1023;
        int h = nn >> 6, d = nn & 63;
        float bval = (mat == 0 ? b0 : (mat == 1 ? b1 : b2))[nn];
        int mb = m0 + wm * 64 + i * 16 + lg * 4;
        if (mat < 2) {  // Q or K: RoPE (even/odd feature pair = adjacent lanes)
          int p = d >> 1;
          float sgn = (d & 1) ? 1.0f : -1.0f;
          u16* dst = (mat == 0) ? Qg : Kg;
#pragma unroll
          for (int r = 0; r < 4; ++r) {
            int m = mb + r, t = m & 2047, b = m >> 11;
            float val = v[r] + bval;
            float c = fcos[t * 32 + p], s = fsin[t * 32 + p];
            float partner = __shfl_xor(val, 1);
            float rv = val * c + sgn * partner * s;
            dst[((size_t)(b * 16 + h) * 2048 + t) * 64 + d] = f2bf(rv);
          }
        } else {  // V
#pragma unroll
          for (int r = 0; r < 4; ++r) {
            int m = mb + r, t = m & 2047, b = m >> 11;
            Vg[((size_t)(b * 16 + h) * 2048 + t) * 64 + d] = f2bf(v[r] + bval);
          }
        }
      }
    }
  } else {
#pragma unroll
    for (int i = 0; i < 4; ++i) {
#pragma unroll
      for (int j = 0; j < 4; ++j) {
        int n = n0 + wn * 64 + j * 16 + lr;
        float bval = b0[n];
        int mb = m0 + wm * 64 + i * 16 + lg * 4;
#pragma unroll
        for (int r = 0; r < 4; ++r)
          outF[(size_t)(mb + r) * 1024 + n] = acc[i][j][r] + bval;
      }
    }
  }
}

// ---------------- flash attention (paired causal tiles) ----------------
// grid: (16, B*H), 4 waves/block. Block x handles q-tiles iA=x and iB=31-x of
// head blockIdx.y: both consume KV tiles 0..iX, so K/V frags are loaded ONCE
// per step and feed two independent QK->softmax->PV chains (2x ILP). Every
// block does exactly 33 tile-steps -> perfect causal load balance.
__global__ __launch_bounds__(256, 2) void k_attn(const u16* __restrict__ Qg,
                                                 const u16* __restrict__ Kg,
                                                 const u16* __restrict__ Vt,
                                                 u16* __restrict__ Ab) {
  __shared__ u16 PA_lds[4][16][72];
  __shared__ u16 PB_lds[4][16][72];
  const int tid = threadIdx.x, lane = tid & 63, w = tid >> 6;
  const int lr = lane & 15, lg = lane >> 4;
  const int iA = blockIdx.x;        // 0..15
  const int iB = 31 - iA;           // 16..31
  const int bh = blockIdx.y;        // b*16+h
  const size_t qkbase = (size_t)bh * 2048 * 64;
  const int qrowA = iA * 64 + w * 16;
  const int qrowB = iB * 64 + w * 16;

  bf16x8 aQA[2], aQB[2];
#pragma unroll
  for (int c = 0; c < 2; ++c) {
    aQA[c] = *(const bf16x8*)&Qg[qkbase + (size_t)(qrowA + lr) * 64 + lg * 8 + c * 32];
    aQB[c] = *(const bf16x8*)&Qg[qkbase + (size_t)(qrowB + lr) * 64 + lg * 8 + c * 32];
  }

  f32x4 accA[4] = {}, accB[4] = {};
  float mA[4], lA[4], mB[4], lB[4];
#pragma unroll
  for (int r = 0; r < 4; ++r) { mA[r] = -1e30f; lA[r] = 0.f; mB[r] = -1e30f; lB[r] = 0.f; }

  bf16x8 k0buf[4][2], k1buf[4][2];
  // preload K tile 0 into k0buf
#pragma unroll
  for (int nt = 0; nt < 4; ++nt) {
    const u16* kp = &Kg[qkbase + (size_t)(nt * 16 + lr) * 64 + lg * 8];
    k0buf[nt][0] = *(const bf16x8*)kp;
    k0buf[nt][1] = *(const bf16x8*)(kp + 32);
  }

  // one softmax chain (max-reduce, exp, sum-reduce, rescale, P->LDS)
  auto chain = [&](float (&p)[4][4], float (&m_run)[4], float (&l_run)[4],
                   f32x4 (&acc_o)[4], u16 (&P_lds)[4][16][72]) {
    float pm[4], alpha[4], rs[4];
#pragma unroll
    for (int r = 0; r < 4; ++r)
      pm[r] = fmaxf(fmaxf(p[0][r], p[1][r]), fmaxf(p[2][r], p[3][r]));
#pragma unroll
    for (int off = 1; off < 16; off <<= 1)
#pragma unroll
      for (int r = 0; r < 4; ++r) pm[r] = fmaxf(pm[r], __shfl_xor(pm[r], off));
#pragma unroll
    for (int r = 0; r < 4; ++r) {
      float mn = fmaxf(m_run[r], pm[r]);
      alpha[r] = __expf(m_run[r] - mn);
      m_run[r] = mn;
    }
#pragma unroll
    for (int nt = 0; nt < 4; ++nt)
#pragma unroll
      for (int r = 0; r < 4; ++r) p[nt][r] = __expf(p[nt][r] - m_run[r]);
#pragma unroll
    for (int r = 0; r < 4; ++r) rs[r] = (p[0][r] + p[1][r]) + (p[2][r] + p[3][r]);
#pragma unroll
    for (int off = 1; off < 16; off <<= 1)
#pragma unroll
      for (int r = 0; r < 4; ++r) rs[r] += __shfl_xor(rs[r], off);
#pragma unroll
    for (int r = 0; r < 4; ++r) l_run[r] = l_run[r] * alpha[r] + rs[r];
#pragma unroll
    for (int j = 0; j < 4; ++j)
#pragma unroll
      for (int r = 0; r < 4; ++r) acc_o[j][r] *= alpha[r];
#pragma unroll
    for (int nt = 0; nt < 4; ++nt)
#pragma unroll
      for (int r = 0; r < 4; ++r)
        P_lds[w][lg * 4 + r][nt * 16 + lr] = f2bf(p[nt][r]);
  };

  // one full tile-step using kcur, prefetching into knxt
  auto step = [&](bf16x8 (&kcur)[4][2], bf16x8 (&knxt)[4][2], int kt) {
    const int kv0 = kt * 64;
    const bool doA = (kt <= iA);
    // QK^T both chains
    f32x4 sB[4], sA[4];
#pragma unroll
    for (int nt = 0; nt < 4; ++nt) {
      f32x4 s = {};
      s = __builtin_amdgcn_mfma_f32_16x16x32_bf16(aQB[0], kcur[nt][0], s, 0, 0, 0);
      s = __builtin_amdgcn_mfma_f32_16x16x32_bf16(aQB[1], kcur[nt][1], s, 0, 0, 0);
      sB[nt] = s;
    }
    if (doA) {
#pragma unroll
      for (int nt = 0; nt < 4; ++nt) {
        f32x4 s = {};
        s = __builtin_amdgcn_mfma_f32_16x16x32_bf16(aQA[0], kcur[nt][0], s, 0, 0, 0);
        s = __builtin_amdgcn_mfma_f32_16x16x32_bf16(aQA[1], kcur[nt][1], s, 0, 0, 0);
        sA[nt] = s;
      }
    }
    // prefetch next K tile (hidden under softmax)
    if (kt < iB) {
#pragma unroll
      for (int nt = 0; nt < 4; ++nt) {
        const u16* kp = &Kg[qkbase + (size_t)(kv0 + 64 + nt * 16 + lr) * 64 + lg * 8];
        knxt[nt][0] = *(const bf16x8*)kp;
        knxt[nt][1] = *(const bf16x8*)(kp + 32);
      }
    }
    // V loads for this tile (consumed after softmax)
    bf16x8 vc[4][2];
#pragma unroll
    for (int j = 0; j < 4; ++j) {
      const u16* vp = &Vt[(size_t)(bh * 64 + j * 16 + lr) * 2048 + kv0 + lg * 8];
      vc[j][0] = *(const bf16x8*)vp;
      vc[j][1] = *(const bf16x8*)(vp + 32);
    }
    // scale + mask
    float pB[4][4], pA[4][4];
#pragma unroll
    for (int nt = 0; nt < 4; ++nt)
#pragma unroll
      for (int r = 0; r < 4; ++r) {
        float xB = sB[nt][r] * 0.125f;
        if (kt == iB && (kv0 + nt * 16 + lr > qrowB + lg * 4 + r)) xB = -1e30f;
        pB[nt][r] = xB;
      }
    if (doA) {
#pragma unroll
      for (int nt = 0; nt < 4; ++nt)
#pragma unroll
        for (int r = 0; r < 4; ++r) {
          float xA = sA[nt][r] * 0.125f;
          if (kt == iA && (kv0 + nt * 16 + lr > qrowA + lg * 4 + r)) xA = -1e30f;
          pA[nt][r] = xA;
        }
    }
    // softmax chains (independent -> scheduler interleaves)
    chain(pB, mB, lB, accB, PB_lds);
    if (doA) chain(pA, mA, lA, accA, PA_lds);
    asm volatile("s_waitcnt lgkmcnt(0)" ::: "memory");
    __builtin_amdgcn_sched_barrier(0);
    bf16x8 aPB0 = *(const bf16x8*)&PB_lds[w][lr][lg * 8];
    bf16x8 aPB1 = *(const bf16x8*)&PB_lds[w][lr][lg * 8 + 32];
#pragma unroll
    for (int j = 0; j < 4; ++j) {
      accB[j] = __builtin_amdgcn_mfma_f32_16x16x32_bf16(aPB0, vc[j][0], accB[j], 0, 0, 0);
      accB[j] = __builtin_amdgcn_mfma_f32_16x16x32_bf16(aPB1, vc[j][1], accB[j], 0, 0, 0);
    }
    if (doA) {
      bf16x8 aPA0 = *(const bf16x8*)&PA_lds[w][lr][lg * 8];
      bf16x8 aPA1 = *(const bf16x8*)&PA_lds[w][lr][lg * 8 + 32];
#pragma unroll
      for (int j = 0; j < 4; ++j) {
        accA[j] = __builtin_amdgcn_mfma_f32_16x16x32_bf16(aPA0, vc[j][0], accA[j], 0, 0, 0);
        accA[j] = __builtin_amdgcn_mfma_f32_16x16x32_bf16(aPA1, vc[j][1], accA[j], 0, 0, 0);
      }
    }
  };

  // even/odd unroll alternating K buffers (no runtime-indexed reg arrays)
  int kt = 0;
  while (true) {
    step(k0buf, k1buf, kt);
    ++kt; if (kt > iB) break;
    step(k1buf, k0buf, kt);
    ++kt; if (kt > iB) break;
  }

  const int b = bh >> 4, h = bh & 15;
#pragma unroll
  for (int j = 0; j < 4; ++j)
#pragma unroll
    for (int r = 0; r < 4; ++r) {
      int qA = qrowA + lg * 4 + r;
      int qB = qrowB + lg * 4 + r;
      Ab[(size_t)(b * 2048 + qA) * 1024 + h * 64 + j * 16 + lr] = f2bf(accA[j][r] / lA[r]);
      Ab[(size_t)(b * 2048 + qB) * 1024 + h * 64 + j * 16 + lr] = f2bf(accB[j][r] / lB[r]);
    }
}

extern "C" void kernel_launch(void* const* d_in, const int* in_sizes, int n_in,
                              void* d_out, int out_size, void* d_ws,
                              size_t ws_size, hipStream_t stream) {
  (void)in_sizes; (void)n_in; (void)out_size; (void)ws_size;
  const float* x = (const float*)d_in[0];
  // d_in[1] = mask (tril) — causal handled analytically
  const float* fcos = (const float*)d_in[2];
  const float* fsin = (const float*)d_in[3];
  const float* wq = (const float*)d_in[4];
  const float* bq = (const float*)d_in[5];
  const float* wk = (const float*)d_in[6];
  const float* bk = (const float*)d_in[7];
  const float* wv = (const float*)d_in[8];
  const float* bv = (const float*)d_in[9];
  const float* wo = (const float*)d_in[10];
  const float* bo = (const float*)d_in[11];
  float* out = (float*)d_out;
  char* ws = (char*)d_ws;
  const size_t MB = 1024 * 1024;
  u16* Xb  = (u16*)(ws);
  u16* Wt  = (u16*)(ws + 8 * MB);
  u16* Wot = (u16*)(ws + 14 * MB);
  u16* Qg  = (u16*)(ws + 16 * MB);
  u16* Kg  = (u16*)(ws + 24 * MB);
  u16* Vg  = (u16*)(ws + 32 * MB);
  u16* Vt  = (u16*)(ws + 40 * MB);
  u16* Ab  = Xb;  // x no longer needed after QKV GEMM

  k_cvt<<<2048, 256, 0, stream>>>(x, Xb);
  k_trw<<<dim3(32, 32, 4), 256, 0, stream>>>(wq, wk, wv, wo, Wt, Wot);
  k_gemm<0><<<dim3(24, 32), 256, 0, stream>>>(Xb, Wt, bq, bk, bv, fcos, fsin,
                                              Qg, Kg, Vg, nullptr);
  k_trv<<<dim3(32, 32), 256, 0, stream>>>(Vg, Vt);
  k_attn<<<dim3(16, 32), 256, 0, stream>>>(Qg, Kg, Vt, Ab);
  k_gemm<1><<<dim3(8, 32), 256, 0, stream>>>(Ab, Wot, bo, nullptr, nullptr,
                                             nullptr, nullptr, nullptr, nullptr,
                                             nullptr, out);
}

// Round 7
// 288.244 us; speedup vs baseline: 1.7474x; 1.3698x over previous
//
#include <hip/hip_runtime.h>
#include <hip/hip_bf16.h>

// CausalSelfAttention (B=2,T=2048,C=1024,H=16,DH=64) — bf16 MFMA implementation.
// ws layout (bytes):
//   [0,8M)    Xb  : x as bf16 [4096][1024]   (reused as Ab = attention out)
//   [8M,14M)  Wt  : [wq;wk;wv]^T bf16 [3072][1024]  (Wt[n][k]=W[k][n])
//   [14M,16M) Wot : wo^T bf16 [1024][1024]
//   [16M,24M) Qg  : [b][h][t][d] bf16 (post-RoPE)
//   [24M,32M) Kg  : [b][h][t][d] bf16 (post-RoPE)
//   [32M,40M) Vg  : [b][h][t][d] bf16
//   [40M,48M) Vt  : [b][h][d][t] bf16

typedef __attribute__((ext_vector_type(8))) short bf16x8;
typedef __attribute__((ext_vector_type(4))) float f32x4;
typedef unsigned short u16;

#define DEV __device__ __forceinline__

// global -> LDS direct DMA, 16B per lane. Dest is wave-uniform base + lane*16
// (G21): LDS stays linear; swizzle is applied on the GLOBAL source address and
// mirrored on the ds_read side (same XOR involution both sides).
#define GLDS16(g, l)                                                        \
  __builtin_amdgcn_global_load_lds(                                         \
      (const __attribute__((address_space(1))) void*)(g),                   \
      (__attribute__((address_space(3))) void*)(l), 16, 0, 0)

DEV u16 f2bf(float f) {
  __hip_bfloat16 h = __float2bfloat16(f);
  u16 u; __builtin_memcpy(&u, &h, 2); return u;
}

// ---------------- x fp32 -> bf16 ----------------
__global__ __launch_bounds__(256) void k_cvt(const float* __restrict__ in,
                                             u16* __restrict__ out) {
  int i = (blockIdx.x * 256 + threadIdx.x) * 8;
  float4 a = *(const float4*)(in + i);
  float4 b = *(const float4*)(in + i + 4);
  union { u16 us[8]; uint4 v; } pk;
  pk.us[0] = f2bf(a.x); pk.us[1] = f2bf(a.y); pk.us[2] = f2bf(a.z); pk.us[3] = f2bf(a.w);
  pk.us[4] = f2bf(b.x); pk.us[5] = f2bf(b.y); pk.us[6] = f2bf(b.z); pk.us[7] = f2bf(b.w);
  *(uint4*)(out + i) = pk.v;
}

// ---------------- weight transpose + convert ----------------
// src [1024][1024] fp32 row-major -> dst [1024][1024] bf16 with dst[n][k]=src[k][n]
__global__ __launch_bounds__(256) void k_trw(const float* __restrict__ wq,
                                             const float* __restrict__ wk,
                                             const float* __restrict__ wv,
                                             const float* __restrict__ wo,
                                             u16* __restrict__ Wt,
                                             u16* __restrict__ Wot) {
  __shared__ float tile[32][33];
  const int z = blockIdx.z;
  const float* src = (z == 0) ? wq : (z == 1) ? wk : (z == 2) ? wv : wo;
  u16* dst = (z < 3) ? (Wt + (size_t)z * 1024 * 1024) : Wot;
  const int n0 = blockIdx.x * 32, k0 = blockIdx.y * 32;
  const int tx = threadIdx.x & 31, ty = threadIdx.x >> 5;
#pragma unroll
  for (int rr = 0; rr < 4; ++rr) {
    int k = ty + rr * 8;
    tile[k][tx] = src[(size_t)(k0 + k) * 1024 + n0 + tx];
  }
  __syncthreads();
#pragma unroll
  for (int rr = 0; rr < 4; ++rr) {
    int n = ty + rr * 8;
    dst[(size_t)(n0 + n) * 1024 + k0 + tx] = f2bf(tile[tx][n]);
  }
}

// ---------------- V transpose: [b][h][t][d] -> [b][h][d][t] ----------------
__global__ __launch_bounds__(256) void k_trv(const u16* __restrict__ Vg,
                                             u16* __restrict__ Vt) {
  __shared__ u16 tile[64][72];
  const int tid = threadIdx.x;
  const int bh = blockIdx.y;
  const int t0 = blockIdx.x * 64;
  const int r = tid >> 2, q = tid & 3;
  const u16* src = &Vg[((size_t)bh * 2048 + t0 + r) * 64 + q * 16];
  uint4 u0 = *(const uint4*)src;
  uint4 u1 = *(const uint4*)(src + 8);
  *(uint4*)&tile[r][q * 16] = u0;
  *(uint4*)&tile[r][q * 16 + 8] = u1;
  __syncthreads();
  const int d = tid >> 2;
  union { u16 us[16]; uint4 v[2]; } pk;
#pragma unroll
  for (int i = 0; i < 16; ++i) pk.us[i] = tile[q * 16 + i][d];
  u16* dst = &Vt[((size_t)bh * 64 + d) * 2048 + t0 + q * 16];
  *(uint4*)dst = pk.v[0];
  *(uint4*)(dst + 8) = pk.v[1];
}

// ---------------- GEMM: C[M][*] = A[M][1024] x Bt[n][1024]^T ----------------
// 128x128 tile, BK=32. Staging = global_load_lds 16B direct DMA, linear LDS
// [128][32]; logical k-chunk c of row r lives at slot c ^ ((r>>1)&3) so the
// fragment ds_read_b128 is 2-way-bank only (free, m136). The XOR is applied
// on the global source (pre-swizzle) and on the read address — same involution.
// EPI 0: fused QKV epilogue (bias + RoPE + scatter to Qg/Kg/Vg)
// EPI 1: output projection epilogue (bias + fp32 store)
template <int EPI>
__global__ __launch_bounds__(256) void k_gemm(
    const u16* __restrict__ A, const u16* __restrict__ Bt,
    const float* __restrict__ b0, const float* __restrict__ b1,
    const float* __restrict__ b2, const float* __restrict__ fcos,
    const float* __restrict__ fsin, u16* __restrict__ Qg, u16* __restrict__ Kg,
    u16* __restrict__ Vg, float* __restrict__ outF) {
  __shared__ u16 As[128 * 32];
  __shared__ u16 Bs[128 * 32];
  const int tid = threadIdx.x, lane = tid & 63, wid = tid >> 6;
  const int wm = wid >> 1, wn = wid & 1;
  const int lr = lane & 15, lg = lane >> 4;
  const int m0 = blockIdx.y * 128, n0 = blockIdx.x * 128;
  const int K = 1024;
  f32x4 acc[4][4] = {};

  // staging: tile = 128 rows x 64B = 8 segments of 16 rows x 1KB.
  // wave w DMAs segments {2w, 2w+1} of both A and B (4 instructions/K-step).
  const int srcChunk = (lane & 3) ^ ((lane >> 3) & 3);  // pre-swizzled source
  const int rowIn = lane >> 2;                          // row within segment
  const int seg0 = wid * 2;
  const u16* aSrc0 = &A[(size_t)(m0 + seg0 * 16 + rowIn) * K + srcChunk * 8];
  const u16* aSrc1 = aSrc0 + 16 * K;
  const u16* bSrc0 = &Bt[(size_t)(n0 + seg0 * 16 + rowIn) * K + srcChunk * 8];
  const u16* bSrc1 = bSrc0 + 16 * K;
  u16* aDst0 = &As[seg0 * 512];        // wave-uniform LDS bases
  u16* aDst1 = &As[seg0 * 512 + 512];
  u16* bDst0 = &Bs[seg0 * 512];
  u16* bDst1 = &Bs[seg0 * 512 + 512];

  const int slot = (lg ^ ((lr >> 1) & 3)) * 8;  // swizzled read slot (u16)

  for (int kt = 0; kt < 32; ++kt) {
    const int ko = kt * 32;
    GLDS16(aSrc0 + ko, aDst0);
    GLDS16(aSrc1 + ko, aDst1);
    GLDS16(bSrc0 + ko, bDst0);
    GLDS16(bSrc1 + ko, bDst1);
    __syncthreads();  // compiler drains vmcnt(0) before s_barrier -> data ready
    bf16x8 af[4], bfr[4];
#pragma unroll
    for (int i = 0; i < 4; ++i)
      af[i] = *(const bf16x8*)&As[(wm * 64 + i * 16 + lr) * 32 + slot];
#pragma unroll
    for (int j = 0; j < 4; ++j)
      bfr[j] = *(const bf16x8*)&Bs[(wn * 64 + j * 16 + lr) * 32 + slot];
#pragma unroll
    for (int i = 0; i < 4; ++i)
#pragma unroll
      for (int j = 0; j < 4; ++j)
        acc[i][j] = __builtin_amdgcn_mfma_f32_16x16x32_bf16(af[i], bfr[j],
                                                            acc[i][j], 0, 0, 0);
    __syncthreads();  // all reads done before next DMA overwrites
  }

  if constexpr (EPI == 0) {
#pragma unroll
    for (int i = 0; i < 4; ++i) {
#pragma unroll
      for (int j = 0; j < 4; ++j) {
        f32x4 v = acc[i][j];
        int n = n0 + wn * 64 + j * 16 + lr;
        int mat = n >> 10, nn = n & 1023;
        int h = nn >> 6, d = nn & 63;
        float bval = (mat == 0 ? b0 : (mat == 1 ? b1 : b2))[nn];
        int mb = m0 + wm * 64 + i * 16 + lg * 4;
        if (mat < 2) {  // Q or K: RoPE (even/odd feature pair = adjacent lanes)
          int p = d >> 1;
          float sgn = (d & 1) ? 1.0f : -1.0f;
          u16* dst = (mat == 0) ? Qg : Kg;
#pragma unroll
          for (int r = 0; r < 4; ++r) {
            int m = mb + r, t = m & 2047, b = m >> 11;
            float val = v[r] + bval;
            float c = fcos[t * 32 + p], s = fsin[t * 32 + p];
            float partner = __shfl_xor(val, 1);
            float rv = val * c + sgn * partner * s;
            dst[((size_t)(b * 16 + h) * 2048 + t) * 64 + d] = f2bf(rv);
          }
        } else {  // V
#pragma unroll
          for (int r = 0; r < 4; ++r) {
            int m = mb + r, t = m & 2047, b = m >> 11;
            Vg[((size_t)(b * 16 + h) * 2048 + t) * 64 + d] = f2bf(v[r] + bval);
          }
        }
      }
    }
  } else {
#pragma unroll
    for (int i = 0; i < 4; ++i) {
#pragma unroll
      for (int j = 0; j < 4; ++j) {
        int n = n0 + wn * 64 + j * 16 + lr;
        float bval = b0[n];
        int mb = m0 + wm * 64 + i * 16 + lg * 4;
#pragma unroll
        for (int r = 0; r < 4; ++r)
          outF[(size_t)(mb + r) * 1024 + n] = acc[i][j][r] + bval;
      }
    }
  }
}

// ---------------- flash attention (paired causal tiles) ----------------
// grid: (16, B*H), 4 waves/block. Block x handles q-tiles iA=x and iB=31-x of
// head blockIdx.y: both consume KV tiles 0..iX, so K/V frags are loaded ONCE
// per step and feed two independent QK->softmax->PV chains (2x ILP). Every
// block does exactly 33 tile-steps -> perfect causal load balance.
__global__ __launch_bounds__(256, 2) void k_attn(const u16* __restrict__ Qg,
                                                 const u16* __restrict__ Kg,
                                                 const u16* __restrict__ Vt,
                                                 u16* __restrict__ Ab) {
  __shared__ u16 PA_lds[4][16][72];
  __shared__ u16 PB_lds[4][16][72];
  const int tid = threadIdx.x, lane = tid & 63, w = tid >> 6;
  const int lr = lane & 15, lg = lane >> 4;
  const int iA = blockIdx.x;        // 0..15
  const int iB = 31 - iA;           // 16..31
  const int bh = blockIdx.y;        // b*16+h
  const size_t qkbase = (size_t)bh * 2048 * 64;
  const int qrowA = iA * 64 + w * 16;
  const int qrowB = iB * 64 + w * 16;

  bf16x8 aQA[2], aQB[2];
#pragma unroll
  for (int c = 0; c < 2; ++c) {
    aQA[c] = *(const bf16x8*)&Qg[qkbase + (size_t)(qrowA + lr) * 64 + lg * 8 + c * 32];
    aQB[c] = *(const bf16x8*)&Qg[qkbase + (size_t)(qrowB + lr) * 64 + lg * 8 + c * 32];
  }

  f32x4 accA[4] = {}, accB[4] = {};
  float mA[4], lA[4], mB[4], lB[4];
#pragma unroll
  for (int r = 0; r < 4; ++r) { mA[r] = -1e30f; lA[r] = 0.f; mB[r] = -1e30f; lB[r] = 0.f; }

  bf16x8 k0buf[4][2], k1buf[4][2];
  // preload K tile 0 into k0buf
#pragma unroll
  for (int nt = 0; nt < 4; ++nt) {
    const u16* kp = &Kg[qkbase + (size_t)(nt * 16 + lr) * 64 + lg * 8];
    k0buf[nt][0] = *(const bf16x8*)kp;
    k0buf[nt][1] = *(const bf16x8*)(kp + 32);
  }

  // one softmax chain (max-reduce, exp, sum-reduce, rescale, P->LDS)
  auto chain = [&](float (&p)[4][4], float (&m_run)[4], float (&l_run)[4],
                   f32x4 (&acc_o)[4], u16 (&P_lds)[4][16][72]) {
    float pm[4], alpha[4], rs[4];
#pragma unroll
    for (int r = 0; r < 4; ++r)
      pm[r] = fmaxf(fmaxf(p[0][r], p[1][r]), fmaxf(p[2][r], p[3][r]));
#pragma unroll
    for (int off = 1; off < 16; off <<= 1)
#pragma unroll
      for (int r = 0; r < 4; ++r) pm[r] = fmaxf(pm[r], __shfl_xor(pm[r], off));
#pragma unroll
    for (int r = 0; r < 4; ++r) {
      float mn = fmaxf(m_run[r], pm[r]);
      alpha[r] = __expf(m_run[r] - mn);
      m_run[r] = mn;
    }
#pragma unroll
    for (int nt = 0; nt < 4; ++nt)
#pragma unroll
      for (int r = 0; r < 4; ++r) p[nt][r] = __expf(p[nt][r] - m_run[r]);
#pragma unroll
    for (int r = 0; r < 4; ++r) rs[r] = (p[0][r] + p[1][r]) + (p[2][r] + p[3][r]);
#pragma unroll
    for (int off = 1; off < 16; off <<= 1)
#pragma unroll
      for (int r = 0; r < 4; ++r) rs[r] += __shfl_xor(rs[r], off);
#pragma unroll
    for (int r = 0; r < 4; ++r) l_run[r] = l_run[r] * alpha[r] + rs[r];
#pragma unroll
    for (int j = 0; j < 4; ++j)
#pragma unroll
      for (int r = 0; r < 4; ++r) acc_o[j][r] *= alpha[r];
#pragma unroll
    for (int nt = 0; nt < 4; ++nt)
#pragma unroll
      for (int r = 0; r < 4; ++r)
        P_lds[w][lg * 4 + r][nt * 16 + lr] = f2bf(p[nt][r]);
  };

  // one full tile-step using kcur, prefetching into knxt
  auto step = [&](bf16x8 (&kcur)[4][2], bf16x8 (&knxt)[4][2], int kt) {
    const int kv0 = kt * 64;
    const bool doA = (kt <= iA);
    // QK^T both chains
    f32x4 sB[4], sA[4];
#pragma unroll
    for (int nt = 0; nt < 4; ++nt) {
      f32x4 s = {};
      s = __builtin_amdgcn_mfma_f32_16x16x32_bf16(aQB[0], kcur[nt][0], s, 0, 0, 0);
      s = __builtin_amdgcn_mfma_f32_16x16x32_bf16(aQB[1], kcur[nt][1], s, 0, 0, 0);
      sB[nt] = s;
    }
    if (doA) {
#pragma unroll
      for (int nt = 0; nt < 4; ++nt) {
        f32x4 s = {};
        s = __builtin_amdgcn_mfma_f32_16x16x32_bf16(aQA[0], kcur[nt][0], s, 0, 0, 0);
        s = __builtin_amdgcn_mfma_f32_16x16x32_bf16(aQA[1], kcur[nt][1], s, 0, 0, 0);
        sA[nt] = s;
      }
    }
    // prefetch next K tile (hidden under softmax)
    if (kt < iB) {
#pragma unroll
      for (int nt = 0; nt < 4; ++nt) {
        const u16* kp = &Kg[qkbase + (size_t)(kv0 + 64 + nt * 16 + lr) * 64 + lg * 8];
        knxt[nt][0] = *(const bf16x8*)kp;
        knxt[nt][1] = *(const bf16x8*)(kp + 32);
      }
    }
    // V loads for this tile (consumed after softmax)
    bf16x8 vc[4][2];
#pragma unroll
    for (int j = 0; j < 4; ++j) {
      const u16* vp = &Vt[(size_t)(bh * 64 + j * 16 + lr) * 2048 + kv0 + lg * 8];
      vc[j][0] = *(const bf16x8*)vp;
      vc[j][1] = *(const bf16x8*)(vp + 32);
    }
    // scale + mask
    float pB[4][4], pA[4][4];
#pragma unroll
    for (int nt = 0; nt < 4; ++nt)
#pragma unroll
      for (int r = 0; r < 4; ++r) {
        float xB = sB[nt][r] * 0.125f;
        if (kt == iB && (kv0 + nt * 16 + lr > qrowB + lg * 4 + r)) xB = -1e30f;
        pB[nt][r] = xB;
      }
    if (doA) {
#pragma unroll
      for (int nt = 0; nt < 4; ++nt)
#pragma unroll
        for (int r = 0; r < 4; ++r) {
          float xA = sA[nt][r] * 0.125f;
          if (kt == iA && (kv0 + nt * 16 + lr > qrowA + lg * 4 + r)) xA = -1e30f;
          pA[nt][r] = xA;
        }
    }
    // softmax chains (independent -> scheduler interleaves)
    chain(pB, mB, lB, accB, PB_lds);
    if (doA) chain(pA, mA, lA, accA, PA_lds);
    asm volatile("s_waitcnt lgkmcnt(0)" ::: "memory");
    __builtin_amdgcn_sched_barrier(0);
    bf16x8 aPB0 = *(const bf16x8*)&PB_lds[w][lr][lg * 8];
    bf16x8 aPB1 = *(const bf16x8*)&PB_lds[w][lr][lg * 8 + 32];
#pragma unroll
    for (int j = 0; j < 4; ++j) {
      accB[j] = __builtin_amdgcn_mfma_f32_16x16x32_bf16(aPB0, vc[j][0], accB[j], 0, 0, 0);
      accB[j] = __builtin_amdgcn_mfma_f32_16x16x32_bf16(aPB1, vc[j][1], accB[j], 0, 0, 0);
    }
    if (doA) {
      bf16x8 aPA0 = *(const bf16x8*)&PA_lds[w][lr][lg * 8];
      bf16x8 aPA1 = *(const bf16x8*)&PA_lds[w][lr][lg * 8 + 32];
#pragma unroll
      for (int j = 0; j < 4; ++j) {
        accA[j] = __builtin_amdgcn_mfma_f32_16x16x32_bf16(aPA0, vc[j][0], accA[j], 0, 0, 0);
        accA[j] = __builtin_amdgcn_mfma_f32_16x16x32_bf16(aPA1, vc[j][1], accA[j], 0, 0, 0);
      }
    }
  };

  // even/odd unroll alternating K buffers (no runtime-indexed reg arrays)
  int kt = 0;
  while (true) {
    step(k0buf, k1buf, kt);
    ++kt; if (kt > iB) break;
    step(k1buf, k0buf, kt);
    ++kt; if (kt > iB) break;
  }

  const int b = bh >> 4, h = bh & 15;
#pragma unroll
  for (int j = 0; j < 4; ++j)
#pragma unroll
    for (int r = 0; r < 4; ++r) {
      int qA = qrowA + lg * 4 + r;
      int qB = qrowB + lg * 4 + r;
      Ab[(size_t)(b * 2048 + qA) * 1024 + h * 64 + j * 16 + lr] = f2bf(accA[j][r] / lA[r]);
      Ab[(size_t)(b * 2048 + qB) * 1024 + h * 64 + j * 16 + lr] = f2bf(accB[j][r] / lB[r]);
    }
}

extern "C" void kernel_launch(void* const* d_in, const int* in_sizes, int n_in,
                              void* d_out, int out_size, void* d_ws,
                              size_t ws_size, hipStream_t stream) {
  (void)in_sizes; (void)n_in; (void)out_size; (void)ws_size;
  const float* x = (const float*)d_in[0];
  // d_in[1] = mask (tril) — causal handled analytically
  const float* fcos = (const float*)d_in[2];
  const float* fsin = (const float*)d_in[3];
  const float* wq = (const float*)d_in[4];
  const float* bq = (const float*)d_in[5];
  const float* wk = (const float*)d_in[6];
  const float* bk = (const float*)d_in[7];
  const float* wv = (const float*)d_in[8];
  const float* bv = (const float*)d_in[9];
  const float* wo = (const float*)d_in[10];
  const float* bo = (const float*)d_in[11];
  float* out = (float*)d_out;
  char* ws = (char*)d_ws;
  const size_t MB = 1024 * 1024;
  u16* Xb  = (u16*)(ws);
  u16* Wt  = (u16*)(ws + 8 * MB);
  u16* Wot = (u16*)(ws + 14 * MB);
  u16* Qg  = (u16*)(ws + 16 * MB);
  u16* Kg  = (u16*)(ws + 24 * MB);
  u16* Vg  = (u16*)(ws + 32 * MB);
  u16* Vt  = (u16*)(ws + 40 * MB);
  u16* Ab  = Xb;  // x no longer needed after QKV GEMM

  k_cvt<<<2048, 256, 0, stream>>>(x, Xb);
  k_trw<<<dim3(32, 32, 4), 256, 0, stream>>>(wq, wk, wv, wo, Wt, Wot);
  k_gemm<0><<<dim3(24, 32), 256, 0, stream>>>(Xb, Wt, bq, bk, bv, fcos, fsin,
                                              Qg, Kg, Vg, nullptr);
  k_trv<<<dim3(32, 32), 256, 0, stream>>>(Vg, Vt);
  k_attn<<<dim3(16, 32), 256, 0, stream>>>(Qg, Kg, Vt, Ab);
  k_gemm<1><<<dim3(8, 32), 256, 0, stream>>>(Ab, Wot, bo, nullptr, nullptr,
                                             nullptr, nullptr, nullptr, nullptr,
                                             nullptr, out);
}